// Round 1
// baseline (361.163 us; speedup 1.0000x reference)
//
#include <hip/hip_runtime.h>

#define B_    512
#define NI    1152
#define DI    8
#define NO    10
#define DO    16

#define BT      16            // batch per block
#define NBT     (B_/BT)       // 32 batch tiles
#define NCHUNKS 16
#define NCH     (NI/NCHUNKS)  // 72 n per chunk
#define NG      4             // n's staged per LDS round
#define WPAD    132           // padded per-o stride (floats) in W LDS tile
#define XPAD    (NCH*DI + 4)  // padded per-b stride (floats) in x LDS tile

// One routing iteration: recompute x_hat on the fly, (optionally) logits from
// outprev + softmax over o, accumulate s partials per n-chunk.
template<bool UNIFORM>
__global__ __launch_bounds__(256) void caps_iter(
    const float* __restrict__ x,        // [B][NI][DI]
    const float* __restrict__ w,        // [NO][NI][DO][DI]
    const float* __restrict__ outprev,  // [B][NO][DO] running sum of outputs
    float* __restrict__ s_part)         // [NCHUNKS][B][NO][DO]
{
    const int tid = threadIdx.x;
    const int bg  = tid >> 4;          // local batch index 0..15
    const int o   = tid & 15;          // capsule lane; active if < NO
    const int ow  = (o < NO) ? o : 0;  // clamped for LDS reads
    const int bt  = blockIdx.x / NCHUNKS;
    const int nc  = blockIdx.x % NCHUNKS;
    const int b   = bt * BT + bg;
    const int n0  = nc * NCH;

    __shared__ float xs[BT][XPAD];            // 16*580*4 = 37120 B
    __shared__ float wsh[NG][NO][WPAD];       // 4*10*132*4 = 21120 B

    // stage x tile: contiguous (n,j) runs per local batch row
    {
        const float* xsrc = x + (size_t)(bt * BT) * NI * DI + (size_t)n0 * DI;
        for (int idx = tid; idx < BT * NCH * DI; idx += 256) {
            int bl  = idx / (NCH * DI);
            int rem = idx % (NCH * DI);
            xs[bl][rem] = xsrc[(size_t)bl * NI * DI + rem];
        }
    }

    float op[DO];
    if constexpr (!UNIFORM) {
        if (o < NO) {
            const float* p = outprev + ((size_t)b * NO + o) * DO;
            #pragma unroll
            for (int d = 0; d < DO; ++d) op[d] = p[d];
        } else {
            #pragma unroll
            for (int d = 0; d < DO; ++d) op[d] = 0.f;
        }
    }

    float sacc[DO];
    #pragma unroll
    for (int d = 0; d < DO; ++d) sacc[d] = 0.f;

    for (int ng = 0; ng < NCH / NG; ++ng) {
        __syncthreads();   // protect previous round's wsh reads
        // stage W[:, n0+ng*NG .. +NG, :, :] -> LDS (coalesced 128-float runs)
        for (int idx = tid; idx < NO * NG * DO * DI; idx += 256) {
            int oo  = idx / (NG * DO * DI);
            int rem = idx % (NG * DO * DI);
            int nn  = rem / (DO * DI);
            int dj  = rem % (DO * DI);
            wsh[nn][oo][dj] = w[((size_t)oo * NI + n0 + ng * NG + nn) * (DO * DI) + dj];
        }
        __syncthreads();

        #pragma unroll
        for (int nn = 0; nn < NG; ++nn) {
            const int nl = ng * NG + nn;
            float xv[DI];
            #pragma unroll
            for (int j = 0; j < DI; ++j) xv[j] = xs[bg][nl * DI + j];

            // x_hat[o][d] for this (b,n): 16x8 matvec
            float xh[DO];
            #pragma unroll
            for (int d = 0; d < DO; ++d) {
                float a = 0.f;
                #pragma unroll
                for (int j = 0; j < DI; ++j)
                    a = fmaf(wsh[nn][ow][d * DI + j], xv[j], a);
                xh[d] = a;
            }

            float c;
            if constexpr (UNIFORM) {
                c = 0.1f;            // softmax of zeros over 10 capsules
            } else {
                float lg = 0.f;
                #pragma unroll
                for (int d = 0; d < DO; ++d) lg = fmaf(op[d], xh[d], lg);
                if (o >= NO) lg = -1e30f;
                float m = lg;
                #pragma unroll
                for (int s = 1; s < 16; s <<= 1)
                    m = fmaxf(m, __shfl_xor(m, s, 16));
                float e = (o < NO) ? __expf(lg - m) : 0.f;
                float sum = e;
                #pragma unroll
                for (int s = 1; s < 16; s <<= 1)
                    sum += __shfl_xor(sum, s, 16);
                c = e / sum;
            }

            #pragma unroll
            for (int d = 0; d < DO; ++d) sacc[d] = fmaf(c, xh[d], sacc[d]);
        }
    }

    if (o < NO) {
        float* dst = s_part + (((size_t)nc * B_ + b) * NO + o) * DO;
        #pragma unroll
        for (int d = 0; d < DO; ++d) dst[d] = sacc[d];
    }
}

// Reduce s partials over chunks, squash, and update outsum / final output.
// MODE 0: outsum = squash(s)   (after iter 0)
// MODE 1: outsum += squash(s)  (after iter 1; logits are linear in outputs)
// MODE 2: dout = squash(s)     (final)
template<int MODE>
__global__ __launch_bounds__(256) void caps_squash(
    const float* __restrict__ s_part,
    float* __restrict__ outsum,
    float* __restrict__ dout)
{
    const int g  = blockIdx.x * 256 + threadIdx.x;   // 0 .. B*NO*DO
    const int bod = g;                               // [b][o][d] flat
    float s = 0.f;
    #pragma unroll
    for (int c = 0; c < NCHUNKS; ++c)
        s += s_part[(size_t)c * B_ * NO * DO + bod];

    // norm^2 over d: 16-lane groups are exactly (b,o) rows (160 % 16 == 0)
    float n2 = s * s;
    #pragma unroll
    for (int m = 1; m < 16; m <<= 1) n2 += __shfl_xor(n2, m, 16);

    float norm  = sqrtf(n2);
    float scale = n2 / ((1.f + n2) * (norm + 1e-8f));
    float v = scale * s;

    if constexpr (MODE == 0)      outsum[bod] = v;
    else if constexpr (MODE == 1) outsum[bod] += v;
    else                          dout[bod] = v;
}

extern "C" void kernel_launch(void* const* d_in, const int* in_sizes, int n_in,
                              void* d_out, int out_size, void* d_ws, size_t ws_size,
                              hipStream_t stream) {
    const float* x = (const float*)d_in[0];   // [512][1152][8]
    const float* w = (const float*)d_in[1];   // [10][1152][16][8]
    float* out = (float*)d_out;               // [512][10][16]

    float* s_part = (float*)d_ws;                              // NCHUNKS*B*NO*DO f32
    float* outsum = s_part + (size_t)NCHUNKS * B_ * NO * DO;   // B*NO*DO f32

    dim3 gI(NBT * NCHUNKS), bI(256);
    dim3 gS((B_ * NO * DO) / 256), bS(256);

    // iter 0: uniform c = 1/10
    caps_iter<true ><<<gI, bI, 0, stream>>>(x, w, nullptr, s_part);
    caps_squash<0><<<gS, bS, 0, stream>>>(s_part, outsum, nullptr);
    // iter 1: logits = <out0, x_hat>
    caps_iter<false><<<gI, bI, 0, stream>>>(x, w, outsum, s_part);
    caps_squash<1><<<gS, bS, 0, stream>>>(s_part, outsum, nullptr);
    // iter 2: logits = <out0+out1, x_hat>
    caps_iter<false><<<gI, bI, 0, stream>>>(x, w, outsum, s_part);
    caps_squash<2><<<gS, bS, 0, stream>>>(s_part, nullptr, out);
}

// Round 2
// 200.894 us; speedup vs baseline: 1.7978x; 1.7978x over previous
//
#include <hip/hip_runtime.h>
#include <hip/hip_bf16.h>

#define B_    512
#define NI    1152
#define DI    8
#define NO    10
#define DO    16
#define BT    16
#define NBT   (B_/BT)         // 32
#define NCHUNKS 16
#define NCH   (NI/NCHUNKS)    // 72 n per chunk
#define NG    8               // n staged per round
#define NR    (NCH/NG)        // 9 rounds
#define XSTRIDE 584           // ushort per b-row: 72*8=576 + 8 pad (bank spread)

typedef __attribute__((ext_vector_type(8))) short   bf16x8;
typedef __attribute__((ext_vector_type(4))) float   f32x4;
typedef __attribute__((ext_vector_type(4))) unsigned short u16x4;

union LdsU {
    struct {
        unsigned short xs[BT * XSTRIDE];      // 18688 B  x tile (bf16)
        unsigned short wsh[NG * NO * 128];    // 20480 B  W round tile (bf16)
    } s;
    float red[3][16 * 168];                   // 32256 B  cross-wave reduce
};

__device__ inline unsigned short f2bf(float f) {
    __hip_bfloat16 h = __float2bfloat16(f);
    return *reinterpret_cast<unsigned short*>(&h);
}

// One routing iteration. Recomputes x_hat via MFMA; softmax over o is
// lane-local; accumulates s partials per n-chunk.
template<bool UNIFORM>
__global__ __launch_bounds__(256) void caps_iter(
    const float* __restrict__ x,        // [B][NI][DI] f32
    const float* __restrict__ wt,       // [NO][NI][DO][DI] f32
    const float* __restrict__ outprev,  // [B][NO][DO] f32 (running output sum)
    float* __restrict__ s_part)         // [NCHUNKS][B][NO][DO]
{
    __shared__ LdsU lds;

    const int tid = threadIdx.x;
    const int w   = tid >> 6;      // wave 0..3
    const int l   = tid & 63;
    const int b16 = l & 15;        // C col = batch within tile
    const int hi  = l >> 4;        // C row group: d = hi*4 + r
    const int bt  = blockIdx.x / NCHUNKS;
    const int nc  = blockIdx.x % NCHUNKS;
    const int n0  = nc * NCH;
    const int bg  = bt * BT + b16; // this lane's global batch

    // out fragment: out[bg, o, hi*4 + r]  (only for non-uniform iters)
    f32x4 outf[NO];
    if constexpr (!UNIFORM) {
        #pragma unroll
        for (int o = 0; o < NO; ++o)
            outf[o] = *reinterpret_cast<const f32x4*>(
                &outprev[((size_t)bg * NO + o) * DO + hi * 4]);
    }

    f32x4 sacc[NO];
    #pragma unroll
    for (int o = 0; o < NO; ++o) sacc[o] = (f32x4){0.f, 0.f, 0.f, 0.f};

    // stage x chunk once: [16 b][72 n * 8 j] f32 -> bf16
    for (int g = tid; g < BT * NCH * DI / 4; g += 256) {   // 2304 float4s
        int bl  = g / (NCH * DI / 4);    // /144
        int rem = g % (NCH * DI / 4);
        float4 v = *reinterpret_cast<const float4*>(
            &x[((size_t)(bt * BT + bl) * NI + n0) * DI + rem * 4]);
        u16x4 u = { f2bf(v.x), f2bf(v.y), f2bf(v.z), f2bf(v.w) };
        *reinterpret_cast<u16x4*>(&lds.s.xs[bl * XSTRIDE + rem * 4]) = u;
    }

    for (int r = 0; r < NR; ++r) {
        __syncthreads();   // xs ready (r=0) / prev round's wsh reads done
        // stage W[o, n0+r*8 .. +8, :, :] -> bf16 LDS
        for (int g = tid; g < NO * NG * 128 / 4; g += 256) {  // 2560 float4s
            int o   = g >> 8;          // 256 granules per o
            int rem = g & 255;
            int nn  = rem >> 5;        // 32 granules per n
            int dj  = rem & 31;
            float4 v = *reinterpret_cast<const float4*>(
                &wt[((size_t)o * NI + n0 + r * NG + nn) * 128 + dj * 4]);
            u16x4 u = { f2bf(v.x), f2bf(v.y), f2bf(v.z), f2bf(v.w) };
            *reinterpret_cast<u16x4*>(&lds.s.wsh[(nn * NO + o) * 128 + dj * 4]) = u;
        }
        __syncthreads();

        #pragma unroll
        for (int t = 0; t < 2; ++t) {
            const int nn = 2 * w + t;        // this wave's n within round
            const int nl = r * NG + nn;      // chunk-local n

            // B frag: x[b=l&15, n, j] at k=0..7, zeros elsewhere
            bf16x8 bv = {0,0,0,0,0,0,0,0};
            if (hi == 0)
                bv = *reinterpret_cast<const bf16x8*>(
                    &lds.s.xs[b16 * XSTRIDE + nl * DI]);

            // x_hat for all 10 capsules: C[d, b]
            f32x4 xh[NO];
            #pragma unroll
            for (int o = 0; o < NO; ++o) {
                bf16x8 av = {0,0,0,0,0,0,0,0};
                if (hi == 0)
                    av = *reinterpret_cast<const bf16x8*>(
                        &lds.s.wsh[(nn * NO + o) * 128 + b16 * DI]);
                xh[o] = __builtin_amdgcn_mfma_f32_16x16x32_bf16(
                    av, bv, (f32x4){0.f, 0.f, 0.f, 0.f}, 0, 0, 0);
            }

            float c[NO];
            if constexpr (UNIFORM) {
                #pragma unroll
                for (int o = 0; o < NO; ++o) c[o] = 0.1f;
            } else {
                // logit[o] = sum_d out[b,o,d]*xh[b,o,n,d]; d spread over hi
                #pragma unroll
                for (int o = 0; o < NO; ++o) {
                    float p = outf[o][0] * xh[o][0];
                    p = fmaf(outf[o][1], xh[o][1], p);
                    p = fmaf(outf[o][2], xh[o][2], p);
                    p = fmaf(outf[o][3], xh[o][3], p);
                    p += __shfl_xor(p, 16, 64);
                    p += __shfl_xor(p, 32, 64);
                    c[o] = p;
                }
                // softmax over o (logits are tiny -> no max subtraction)
                float sum = 0.f;
                #pragma unroll
                for (int o = 0; o < NO; ++o) { c[o] = __expf(c[o]); sum += c[o]; }
                float rs = 1.0f / sum;
                #pragma unroll
                for (int o = 0; o < NO; ++o) c[o] *= rs;
            }

            #pragma unroll
            for (int o = 0; o < NO; ++o) {
                #pragma unroll
                for (int q = 0; q < 4; ++q)
                    sacc[o][q] = fmaf(c[o], xh[o][q], sacc[o][q]);
            }
        }
    }

    // cross-wave reduce (waves 1-3 -> LDS, wave 0 sums + stores)
    __syncthreads();
    if (w > 0) {
        #pragma unroll
        for (int o = 0; o < NO; ++o)
            *reinterpret_cast<f32x4*>(
                &lds.red[w - 1][b16 * 168 + o * 16 + hi * 4]) = sacc[o];
    }
    __syncthreads();
    if (w == 0) {
        #pragma unroll
        for (int o = 0; o < NO; ++o) {
            f32x4 v = sacc[o];
            #pragma unroll
            for (int ww = 0; ww < 3; ++ww) {
                f32x4 p = *reinterpret_cast<const f32x4*>(
                    &lds.red[ww][b16 * 168 + o * 16 + hi * 4]);
                v[0] += p[0]; v[1] += p[1]; v[2] += p[2]; v[3] += p[3];
            }
            *reinterpret_cast<f32x4*>(
                &s_part[(((size_t)nc * B_ + bg) * NO + o) * DO + hi * 4]) = v;
        }
    }
}

// Reduce s partials over chunks, squash, update outsum / final output.
template<int MODE>
__global__ __launch_bounds__(256) void caps_squash(
    const float* __restrict__ s_part,
    float* __restrict__ outsum,
    float* __restrict__ dout)
{
    const int bod = blockIdx.x * 256 + threadIdx.x;   // [b][o][d] flat
    float s = 0.f;
    #pragma unroll
    for (int c = 0; c < NCHUNKS; ++c)
        s += s_part[(size_t)c * B_ * NO * DO + bod];

    float n2 = s * s;
    #pragma unroll
    for (int m = 1; m < 16; m <<= 1) n2 += __shfl_xor(n2, m, 16);

    float norm  = sqrtf(n2);
    float scale = n2 / ((1.f + n2) * (norm + 1e-8f));
    float v = scale * s;

    if constexpr (MODE == 0)      outsum[bod] = v;
    else if constexpr (MODE == 1) outsum[bod] += v;
    else                          dout[bod] = v;
}

extern "C" void kernel_launch(void* const* d_in, const int* in_sizes, int n_in,
                              void* d_out, int out_size, void* d_ws, size_t ws_size,
                              hipStream_t stream) {
    const float* x = (const float*)d_in[0];   // [512][1152][8]
    const float* w = (const float*)d_in[1];   // [10][1152][16][8]
    float* out = (float*)d_out;               // [512][10][16]

    float* s_part = (float*)d_ws;                              // 16*512*160 f32
    float* outsum = s_part + (size_t)NCHUNKS * B_ * NO * DO;   // 512*160 f32

    dim3 gI(NBT * NCHUNKS), bI(256);
    dim3 gS((B_ * NO * DO) / 256), bS(256);

    // iter 0: uniform c = 1/10
    caps_iter<true ><<<gI, bI, 0, stream>>>(x, w, nullptr, s_part);
    caps_squash<0><<<gS, bS, 0, stream>>>(s_part, outsum, nullptr);
    // iter 1: logits = <out0, x_hat>
    caps_iter<false><<<gI, bI, 0, stream>>>(x, w, outsum, s_part);
    caps_squash<1><<<gS, bS, 0, stream>>>(s_part, outsum, nullptr);
    // iter 2: logits = <out0+out1, x_hat>
    caps_iter<false><<<gI, bI, 0, stream>>>(x, w, outsum, s_part);
    caps_squash<2><<<gS, bS, 0, stream>>>(s_part, nullptr, out);
}

// Round 3
// 141.896 us; speedup vs baseline: 2.5453x; 1.4158x over previous
//
#include <hip/hip_runtime.h>
#include <hip/hip_bf16.h>

#define B_      512
#define NI      1152
#define DI      8
#define NO      10
#define DO      16
#define BT      16
#define NBT     (B_/BT)        // 32
#define NCHUNKS 32
#define NCH     (NI/NCHUNKS)   // 36 n per chunk
#define NG      4              // n per round (1 per wave)
#define NR      (NCH/NG)       // 9 rounds
#define XROW    296            // ushort per b-row in x tile (288 + 8 pad)
#define OROW    172            // f32 per b-row in outs tile (160 + 12 pad)

typedef __attribute__((ext_vector_type(8))) short bf16x8;
typedef __attribute__((ext_vector_type(4))) float f32x4;
typedef __attribute__((ext_vector_type(4))) unsigned short u16x4;

// workspace layout (bytes)
#define SPART_SZ   ((size_t)NCHUNKS * B_ * NO * DO * 4)   // 10,485,760
#define OUTSUM_SZ  ((size_t)B_ * NO * DO * 4)             //    327,680
#define XB_SZ      ((size_t)NCHUNKS * B_ * XROW * 2)      //  9,699,328
#define WB_SZ      ((size_t)NO * NI * 128 * 2)            //  2,949,120

__device__ inline unsigned short f2bf(float f) {
    __hip_bfloat16 h = __float2bfloat16(f);
    return *reinterpret_cast<unsigned short*>(&h);
}

__device__ inline void gld_lds16(const void* g, void* lds) {
    __builtin_amdgcn_global_load_lds(
        (const __attribute__((address_space(1))) void*)g,
        (__attribute__((address_space(3))) void*)lds, 16, 0, 0);
}

// ---- precompute bf16 tiled copies --------------------------------------
// x[b][n][j] f32 -> xb[nc][bt][bl][XROW] bf16 (row = 288 data + 8 pad)
__global__ __launch_bounds__(256) void cvt_x(
    const float* __restrict__ x, unsigned short* __restrict__ xb)
{
    int t   = blockIdx.x * 256 + threadIdx.x;   // < 1,179,648
    int q   = t % 72;                           // float4 within row
    int rid = t / 72;
    int bl  = rid & 15;
    int bt  = (rid >> 4) & 31;
    int nc  = rid >> 9;
    float4 v = *reinterpret_cast<const float4*>(
        x + ((size_t)(bt * 16 + bl) * NI + nc * NCH) * DI + q * 4);
    u16x4 u = { f2bf(v.x), f2bf(v.y), f2bf(v.z), f2bf(v.w) };
    *reinterpret_cast<u16x4*>(
        xb + ((size_t)(nc * 32 + bt) * 16 + bl) * XROW + q * 4) = u;
}

// w[o][n][d][j] f32 -> wb[nc][r][nn][o][128] bf16 (LDS-image per round)
__global__ __launch_bounds__(256) void cvt_w(
    const float* __restrict__ w, unsigned short* __restrict__ wb)
{
    int t = blockIdx.x * 256 + threadIdx.x;     // < 368,640
    int k = t & 31;                             // float4 within (o,n) row
    int n = (t >> 5) % NI;
    int o = t / (32 * NI);
    float4 v = *reinterpret_cast<const float4*>(
        w + ((size_t)o * NI + n) * 128 + k * 4);
    u16x4 u = { f2bf(v.x), f2bf(v.y), f2bf(v.z), f2bf(v.w) };
    int nc = n / NCH, nl = n % NCH, r = nl >> 2, nn = nl & 3;
    *reinterpret_cast<u16x4*>(
        wb + ((((size_t)nc * NR + r) * NG + nn) * NO + o) * 128 + k * 4) = u;
}

// ---- routing iteration -------------------------------------------------
union LdsU {
    struct {
        unsigned short xs[BT * XROW];          //  9,472 B
        unsigned short wsh[2][NG][NO][128];    // 20,480 B (double-buffered)
        float outs[BT][OROW];                  // 11,008 B
    } s;
    float red[4][2560];                        // 40,960 B (cross-wave reduce)
};

template<bool UNIFORM>
__global__ __launch_bounds__(256, 4) void caps_iter(
    const unsigned short* __restrict__ xb,   // [nc][32][16][XROW] bf16
    const unsigned short* __restrict__ wb,   // [nc][r][nn][o][128] bf16
    const float* __restrict__ outprev,       // [B][NO][DO] f32
    float* __restrict__ s_part)              // [NCHUNKS][B][NO][DO] f32
{
    __shared__ LdsU lds;
    const int tid = threadIdx.x;
    const int w   = tid >> 6;       // wave 0..3 (= nn within round)
    const int l   = tid & 63;
    const int b16 = l & 15;         // C col = batch in tile
    const int hi  = l >> 4;         // C rows hi*4..hi*4+3 = d
    const int bt  = blockIdx.x / NCHUNKS;
    const int nc  = blockIdx.x % NCHUNKS;

    // stage x tile (once) + W round 0, async
    const unsigned short* xsrc = xb + (size_t)(nc * NBT + bt) * BT * XROW;
    for (int g = tid; g < (BT * XROW * 2) / 16; g += 256)        // 592
        gld_lds16(xsrc + g * 8, (char*)lds.s.xs + g * 16);
    const unsigned short* wsrc = wb + (size_t)nc * (NR * NG * NO * 128);
    for (int g = tid; g < (NG * NO * 128 * 2) / 16; g += 256)    // 640
        gld_lds16(wsrc + g * 8, (char*)lds.s.wsh[0] + g * 16);

    if constexpr (!UNIFORM) {
        const float* osrc = outprev + (size_t)bt * BT * NO * DO;
        for (int g = tid; g < BT * NO * DO / 4; g += 256) {      // 640
            int row = g / 40, col = g % 40;
            f32x4 v = *reinterpret_cast<const f32x4*>(osrc + row * 160 + col * 4);
            *reinterpret_cast<f32x4*>(&lds.s.outs[row][col * 4]) = v;
        }
    }

    f32x4 sacc[NO];
    #pragma unroll
    for (int o = 0; o < NO; ++o) sacc[o] = (f32x4){0.f, 0.f, 0.f, 0.f};

    asm volatile("s_waitcnt vmcnt(0)" ::: "memory");
    __syncthreads();

    for (int r = 0; r < NR; ++r) {
        const int cur = r & 1;
        if (r + 1 < NR) {   // prefetch next W round; stays in flight over compute
            const unsigned short* ws2 = wsrc + (size_t)(r + 1) * (NG * NO * 128);
            for (int g = tid; g < 640; g += 256)
                gld_lds16(ws2 + g * 8, (char*)lds.s.wsh[cur ^ 1] + g * 16);
        }

        const int nl = r * NG + w;   // this wave's n within chunk
        bf16x8 bv = {};
        if (hi == 0)
            bv = *reinterpret_cast<const bf16x8*>(&lds.s.xs[b16 * XROW + nl * 8]);

        if constexpr (UNIFORM) {
            #pragma unroll
            for (int o = 0; o < NO; ++o) {
                bf16x8 av = {};
                if (hi == 0)
                    av = *reinterpret_cast<const bf16x8*>(
                        &lds.s.wsh[cur][w][o][b16 * 8]);
                sacc[o] = __builtin_amdgcn_mfma_f32_16x16x32_bf16(
                    av, bv, sacc[o], 0, 0, 0);   // c=const folded at epilogue
            }
        } else {
            f32x4 xh[NO]; float p[NO];
            #pragma unroll
            for (int o = 0; o < NO; ++o) {
                bf16x8 av = {};
                if (hi == 0)
                    av = *reinterpret_cast<const bf16x8*>(
                        &lds.s.wsh[cur][w][o][b16 * 8]);
                xh[o] = __builtin_amdgcn_mfma_f32_16x16x32_bf16(
                    av, bv, (f32x4){0.f, 0.f, 0.f, 0.f}, 0, 0, 0);
            }
            #pragma unroll
            for (int o = 0; o < NO; ++o) {
                f32x4 ov = *reinterpret_cast<const f32x4*>(
                    &lds.s.outs[b16][o * 16 + hi * 4]);
                float t = ov[0] * xh[o][0];
                t = fmaf(ov[1], xh[o][1], t);
                t = fmaf(ov[2], xh[o][2], t);
                t = fmaf(ov[3], xh[o][3], t);
                t += __shfl_xor(t, 16, 64);
                t += __shfl_xor(t, 32, 64);
                p[o] = t;
            }
            float sum = 0.f;
            #pragma unroll
            for (int o = 0; o < NO; ++o) { p[o] = __expf(p[o]); sum += p[o]; }
            float rs = 1.0f / sum;
            #pragma unroll
            for (int o = 0; o < NO; ++o) {
                float cc = p[o] * rs;
                #pragma unroll
                for (int q = 0; q < 4; ++q)
                    sacc[o][q] = fmaf(cc, xh[o][q], sacc[o][q]);
            }
        }
        asm volatile("s_waitcnt vmcnt(0)" ::: "memory");
        __syncthreads();
    }

    // cross-wave reduce via XOR-swizzled LDS (conflict-free), parallel store
    const float scale = UNIFORM ? 0.1f : 1.0f;
    #pragma unroll
    for (int o = 0; o < NO; ++o) {
        int word = (b16 * 160 + o * 16 + hi * 4) ^ ((b16 & 7) << 2);
        *reinterpret_cast<f32x4*>(&lds.red[w][word]) =
            (f32x4){sacc[o][0] * scale, sacc[o][1] * scale,
                    sacc[o][2] * scale, sacc[o][3] * scale};
    }
    __syncthreads();
    float* dst = s_part + (size_t)nc * (B_ * NO * DO) + (size_t)bt * (BT * NO * DO);
    for (int g = tid; g < 640; g += 256) {
        int b  = g / 40;
        int xw = (g * 4) ^ ((b & 7) << 2);
        f32x4 a0 = *reinterpret_cast<const f32x4*>(&lds.red[0][xw]);
        f32x4 a1 = *reinterpret_cast<const f32x4*>(&lds.red[1][xw]);
        f32x4 a2 = *reinterpret_cast<const f32x4*>(&lds.red[2][xw]);
        f32x4 a3 = *reinterpret_cast<const f32x4*>(&lds.red[3][xw]);
        f32x4 s;
        #pragma unroll
        for (int q = 0; q < 4; ++q) s[q] = (a0[q] + a1[q]) + (a2[q] + a3[q]);
        *reinterpret_cast<f32x4*>(dst + g * 4) = s;
    }
}

// ---- reduce chunks + squash --------------------------------------------
template<int MODE>
__global__ __launch_bounds__(256) void caps_squash(
    const float* __restrict__ s_part,
    float* __restrict__ outsum,
    float* __restrict__ dout)
{
    const int bod = blockIdx.x * 256 + threadIdx.x;   // [b][o][d] flat
    float s = 0.f;
    #pragma unroll
    for (int c = 0; c < NCHUNKS; ++c)
        s += s_part[(size_t)c * B_ * NO * DO + bod];

    float n2 = s * s;
    #pragma unroll
    for (int m = 1; m < 16; m <<= 1) n2 += __shfl_xor(n2, m, 16);

    float norm  = sqrtf(n2);
    float scale = n2 / ((1.f + n2) * (norm + 1e-8f));
    float v = scale * s;

    if constexpr (MODE == 0)      outsum[bod] = v;
    else if constexpr (MODE == 1) outsum[bod] += v;
    else                          dout[bod] = v;
}

extern "C" void kernel_launch(void* const* d_in, const int* in_sizes, int n_in,
                              void* d_out, int out_size, void* d_ws, size_t ws_size,
                              hipStream_t stream) {
    const float* x = (const float*)d_in[0];   // [512][1152][8]
    const float* w = (const float*)d_in[1];   // [10][1152][16][8]
    float* out = (float*)d_out;               // [512][10][16]

    char* ws = (char*)d_ws;                   // total ~22.4 MiB
    float*          s_part = (float*)ws;
    float*          outsum = (float*)(ws + SPART_SZ);
    unsigned short* xb     = (unsigned short*)(ws + SPART_SZ + OUTSUM_SZ);
    unsigned short* wb     = (unsigned short*)(ws + SPART_SZ + OUTSUM_SZ + XB_SZ);

    cvt_x<<<dim3(4608), dim3(256), 0, stream>>>(x, xb);
    cvt_w<<<dim3(1440), dim3(256), 0, stream>>>(w, wb);

    dim3 gI(NBT * NCHUNKS), bI(256);              // 1024 blocks = 4/CU
    dim3 gS((B_ * NO * DO) / 256), bS(256);       // 320 blocks

    caps_iter<true ><<<gI, bI, 0, stream>>>(xb, wb, nullptr, s_part);
    caps_squash<0><<<gS, bS, 0, stream>>>(s_part, outsum, nullptr);
    caps_iter<false><<<gI, bI, 0, stream>>>(xb, wb, outsum, s_part);
    caps_squash<1><<<gS, bS, 0, stream>>>(s_part, outsum, nullptr);
    caps_iter<false><<<gI, bI, 0, stream>>>(xb, wb, outsum, s_part);
    caps_squash<2><<<gS, bS, 0, stream>>>(s_part, nullptr, out);
}